// Round 1
// baseline (474.496 us; speedup 1.0000x reference)
//
#include <hip/hip_runtime.h>
#include <math.h>

// ---- problem constants ----
#define BB    4096      // batch
#define NS    51        // NB_STEPS+1 quadrature points
#define TBR   5         // batch rows per integrate block (5*51=255 of 256 threads)
#define NBI   820       // ceil(4096/5) blocks per integral
#define NBF   16        // blocks for out_first (4096/256)
#define GRID_INT (2*NBI + NBF)
#define INV_ALPHA (1.0f/0.9f)

// ---- workspace float offsets ----
#define WS_CCW  0
#define WS_CCS  64
#define WS_LAM  128
#define WS_PMAX 160
#define WS_XM   256
#define WS_X    (WS_XM + BB)
#define WS_X2   (WS_X + BB)

// Clenshaw-Curtis weights/steps + lambda, computed in double to match numpy.
__global__ void k_init(const float* __restrict__ sp, float* __restrict__ ws) {
    int j = threadIdx.x;
    if (j == 0) ws[WS_LAM] = 1.0f / (1.0f + expf(-sp[0]));
    if (j <= 50) {
        const double n = 50.0;
        ws[WS_CCS + j] = (float)cos((double)j * M_PI / n);
        double acc = 0.0;
        for (int a = 0; a <= 50; ++a) {
            double w;
            if (a == 0) w = 1.0;
            else if ((a & 1) == 0) w = 2.0 / (1.0 - (double)a * (double)a);
            else w = 0.0;
            double l;
            if (j == 0) l = 0.5;
            else {
                l = cos((double)(a * j) * M_PI / n);
                if (j == 50) l *= 0.5;
            }
            acc += l * (2.0 / n) * w;
        }
        ws[WS_CCW + j] = (float)acc;
    }
}

// xm[b] = dot(x_[b,:], log_weight)  — one wave per row
__global__ void k_xm(const float* __restrict__ x_, const float* __restrict__ lw,
                     float* __restrict__ xm) {
    int row  = (blockIdx.x * blockDim.x + threadIdx.x) >> 6;
    int lane = threadIdx.x & 63;
    if (row >= BB) return;
    float v = 0.0f;
    for (int i = lane; i < 100; i += 64) v = fmaf(x_[row * 100 + i], lw[i], v);
    #pragma unroll
    for (int off = 32; off > 0; off >>= 1) v += __shfl_xor(v, off, 64);
    if (lane == 0) xm[row] = v;
}

// x = (1-lam)*xm + lam*I1 ; x2 = (1-lam)*xm + lam*I2 ; per-block max(x2)
__global__ void k_pre(const float* __restrict__ xm, const float* __restrict__ out,
                      const float* __restrict__ ws_lam,
                      float* __restrict__ x, float* __restrict__ x2,
                      float* __restrict__ pmax, int first) {
    int b = blockIdx.x * 256 + threadIdx.x;
    float lam = ws_lam[0];
    float i1 = first ? 0.0f : out[b];
    float i2 = first ? 0.0f : out[2 * BB + b];
    float m  = xm[b];
    float xv  = (1.0f - lam) * m + lam * i1;
    float x2v = (1.0f - lam) * m + lam * i2;
    x[b] = xv;
    x2[b] = x2v;
    __shared__ float red[256];
    red[threadIdx.x] = x2v;
    __syncthreads();
    #pragma unroll
    for (int off = 128; off > 0; off >>= 1) {
        if (threadIdx.x < off)
            red[threadIdx.x] = fmaxf(red[threadIdx.x], red[threadIdx.x + off]);
        __syncthreads();
    }
    if (threadIdx.x == 0) pmax[blockIdx.x] = red[0];
}

// Full integrand: MLP(5->64->64->64->1, relu x3, elu) -> z=y+1 -> powers -> relu(Wf @ 1/(f+1))
// Weights read at wave-uniform compile-time offsets -> scalar loads; activations in regs.
__device__ __forceinline__ float eval_mlp(
    float xin, float h0, float h1, float h2, float h3,
    const float* __restrict__ W0, const float* __restrict__ b0,
    const float* __restrict__ W1, const float* __restrict__ b1,
    const float* __restrict__ W2, const float* __restrict__ b2,
    const float* __restrict__ W3, const float* __restrict__ b3,
    const float* __restrict__ Wf,
    float p0, float p1, float p2, float p3, float p4)
{
    float a[64], c[64];
    #pragma unroll
    for (int j = 0; j < 64; ++j) {
        float acc = b0[j];
        acc = fmaf(W0[j * 5 + 0], xin, acc);
        acc = fmaf(W0[j * 5 + 1], h0, acc);
        acc = fmaf(W0[j * 5 + 2], h1, acc);
        acc = fmaf(W0[j * 5 + 3], h2, acc);
        acc = fmaf(W0[j * 5 + 4], h3, acc);
        a[j] = fmaxf(acc, 0.0f);
    }
    #pragma unroll
    for (int j = 0; j < 64; ++j) {
        float acc = b1[j];
        #pragma unroll
        for (int k = 0; k < 64; ++k) acc = fmaf(W1[j * 64 + k], a[k], acc);
        c[j] = fmaxf(acc, 0.0f);
    }
    #pragma unroll
    for (int j = 0; j < 64; ++j) {
        float acc = b2[j];
        #pragma unroll
        for (int k = 0; k < 64; ++k) acc = fmaf(W2[j * 64 + k], c[k], acc);
        a[j] = fmaxf(acc, 0.0f);
    }
    float y = b3[0];
    #pragma unroll
    for (int k = 0; k < 64; ++k) y = fmaf(W3[k], a[k], y);
    if (y <= 0.0f) y = __expf(y) - 1.0f;   // elu
    float z = y + 1.0f;                    // z >= 0
    float lg = __logf(z);                  // z=0 -> -inf -> exp -> 0 (matches 0**p)
    float g = Wf[0] / (__expf(p0 * lg) + 1.0f)
            + Wf[1] / (__expf(p1 * lg) + 1.0f)
            + Wf[2] / (__expf(p2 * lg) + 1.0f)
            + Wf[3] / (__expf(p3 * lg) + 1.0f)
            + Wf[4] / (__expf(p4 * lg) + 1.0f);
    return fmaxf(g, 0.0f);
}

// Blocks [0,NBI): I1 quadrature (f1, 0 -> x).  [NBI,2*NBI): I2 (f2, x2 -> xmax).
// [2*NBI, +NBF): out_first = f1(x2, h).
__global__ __launch_bounds__(256) void k_int(
    const float* __restrict__ xarr, const float* __restrict__ x2arr,
    const float* __restrict__ pmax, const float* __restrict__ h_,
    const float* __restrict__ ccw, const float* __restrict__ ccs,
    const float* __restrict__ f1W0, const float* __restrict__ f1b0,
    const float* __restrict__ f1W1, const float* __restrict__ f1b1,
    const float* __restrict__ f1W2, const float* __restrict__ f1b2,
    const float* __restrict__ f1W3, const float* __restrict__ f1b3,
    const float* __restrict__ f1Wf,
    const float* __restrict__ f2W0, const float* __restrict__ f2b0,
    const float* __restrict__ f2W1, const float* __restrict__ f2b1,
    const float* __restrict__ f2W2, const float* __restrict__ f2b2,
    const float* __restrict__ f2W3, const float* __restrict__ f2b3,
    const float* __restrict__ f2Wf,
    float* __restrict__ out)
{
    const int blk = blockIdx.x;
    const int tid = threadIdx.x;
    int kind, b_base = 0, b, s = 0;
    if (blk < NBI)            { kind = 0; b_base = blk * TBR; }
    else if (blk < 2 * NBI)   { kind = 1; b_base = (blk - NBI) * TBR; }
    else                      { kind = 2; }

    float xmax = 0.0f, xin;
    if (kind == 2) {
        b = (blk - 2 * NBI) * 256 + tid;       // exactly covers 4096
        xin = x2arr[b];
    } else {
        if (kind == 1) {
            float m = pmax[0];
            #pragma unroll
            for (int i = 1; i < 16; ++i) m = fmaxf(m, pmax[i]);
            xmax = m + 10.0f;
        }
        int lb = tid / 51;                      // 0..5 (tid=255 -> 5, padding lane)
        s = tid - lb * 51;
        b = b_base + (lb < TBR - 1 ? lb : TBR - 1);
        if (b > BB - 1) b = BB - 1;             // clamp for last partial block
        float t = (ccs[s] + 1.0f) * 0.5f;
        if (kind == 0) xin = xarr[b] * t;                         // x0 = 0
        else { float x0v = x2arr[b]; xin = x0v + (xmax - x0v) * t; }
    }
    const float4 h4 = ((const float4*)h_)[b];

    const bool u2 = (kind == 1);
    const float* W0 = u2 ? f2W0 : f1W0;  const float* B0 = u2 ? f2b0 : f1b0;
    const float* W1 = u2 ? f2W1 : f1W1;  const float* B1 = u2 ? f2b1 : f1b1;
    const float* W2 = u2 ? f2W2 : f1W2;  const float* B2 = u2 ? f2b2 : f1b2;
    const float* W3 = u2 ? f2W3 : f1W3;  const float* B3 = u2 ? f2b3 : f1b3;
    const float* WF = u2 ? f2Wf : f1Wf;
    const float p0 = u2 ? 1.5f : 1.1f;
    const float p1 = u2 ? 2.0f : 1.1f;
    const float p2 = u2 ? 2.5f : 1.5f;
    const float p3 = u2 ? 3.0f : 2.0f;
    const float p4 = u2 ? 3.5f : 2.5f;

    float val = eval_mlp(xin, h4.x, h4.y, h4.z, h4.w,
                         W0, B0, W1, B1, W2, B2, W3, B3, WF,
                         p0, p1, p2, p3, p4);

    if (kind == 2) { out[BB + b] = val; return; }   // whole block returns together

    __shared__ float red[256];
    red[tid] = ccw[s] * val;
    __syncthreads();
    if (tid < TBR) {
        float sum = 0.0f;
        for (int i = 0; i < NS; ++i) sum += red[tid * NS + i];
        int bo = b_base + tid;
        if (bo < BB) {
            if (kind == 0) out[bo] = sum * xarr[bo] * 0.5f;
            else out[2 * BB + bo] = sum * (xmax - x2arr[bo]) * 0.5f * INV_ALPHA;
        }
    }
}

extern "C" void kernel_launch(void* const* d_in, const int* in_sizes, int n_in,
                              void* d_out, int out_size, void* d_ws, size_t ws_size,
                              hipStream_t stream) {
    const float* x_  = (const float*)d_in[0];
    const float* h_  = (const float*)d_in[1];
    const float* lw  = (const float*)d_in[2];
    const float* sp  = (const float*)d_in[3];
    const float* f1W0 = (const float*)d_in[4];   const float* f1b0 = (const float*)d_in[5];
    const float* f1W1 = (const float*)d_in[6];   const float* f1b1 = (const float*)d_in[7];
    const float* f1W2 = (const float*)d_in[8];   const float* f1b2 = (const float*)d_in[9];
    const float* f1W3 = (const float*)d_in[10];  const float* f1b3 = (const float*)d_in[11];
    const float* f1Wf = (const float*)d_in[12];
    const float* f2W0 = (const float*)d_in[13];  const float* f2b0 = (const float*)d_in[14];
    const float* f2W1 = (const float*)d_in[15];  const float* f2b1 = (const float*)d_in[16];
    const float* f2W2 = (const float*)d_in[17];  const float* f2b2 = (const float*)d_in[18];
    const float* f2W3 = (const float*)d_in[19];  const float* f2b3 = (const float*)d_in[20];
    const float* f2Wf = (const float*)d_in[21];
    float* out = (float*)d_out;
    float* ws  = (float*)d_ws;

    k_init<<<1, 64, 0, stream>>>(sp, ws);
    k_xm<<<(BB * 64) / 256, 256, 0, stream>>>(x_, lw, ws + WS_XM);

    for (int step = 0; step < 2; ++step) {
        k_pre<<<16, 256, 0, stream>>>(ws + WS_XM, out, ws + WS_LAM,
                                      ws + WS_X, ws + WS_X2, ws + WS_PMAX,
                                      step == 0 ? 1 : 0);
        k_int<<<GRID_INT, 256, 0, stream>>>(
            ws + WS_X, ws + WS_X2, ws + WS_PMAX, h_,
            ws + WS_CCW, ws + WS_CCS,
            f1W0, f1b0, f1W1, f1b1, f1W2, f1b2, f1W3, f1b3, f1Wf,
            f2W0, f2b0, f2W1, f2b1, f2W2, f2b2, f2W3, f2b3, f2Wf,
            out);
    }
}

// Round 2
// 314.004 us; speedup vs baseline: 1.5111x; 1.5111x over previous
//
#include <hip/hip_runtime.h>
#include <hip/hip_fp16.h>
#include <math.h>

// ---- problem constants ----
#define BB    4096      // batch
#define NS    51        // NB_STEPS+1 quadrature points
#define TBR   5         // batch rows per integrate block (5*51=255 of 256 threads)
#define NBI   820       // ceil(4096/5) blocks per integral
#define NBF   16        // blocks for out_first (4096/256)
#define GRID_INT (2*NBI + NBF)
#define INV_ALPHA (1.0f/0.9f)

// ---- workspace float offsets ----
#define WS_CCW  0
#define WS_CCS  64
#define WS_LAM  128
#define WS_PMAX 160
#define WS_XM   256
#define WS_X    (WS_XM + BB)
#define WS_X2   (WS_X + BB)
#define WS_WT   16384
// transposed-weight layout within WS_WT (per net: 320 + 4096 + 4096 = 8512)
#define WT_NET  8512
#define WT_W1   320
#define WT_W2   4416

// Clenshaw-Curtis weights/steps + lambda, computed in double to match numpy.
__global__ void k_init(const float* __restrict__ sp, float* __restrict__ ws) {
    int j = threadIdx.x;
    if (j == 0) ws[WS_LAM] = 1.0f / (1.0f + expf(-sp[0]));
    if (j <= 50) {
        const double n = 50.0;
        ws[WS_CCS + j] = (float)cos((double)j * M_PI / n);
        double acc = 0.0;
        for (int a = 0; a <= 50; ++a) {
            double w;
            if (a == 0) w = 1.0;
            else if ((a & 1) == 0) w = 2.0 / (1.0 - (double)a * (double)a);
            else w = 0.0;
            double l;
            if (j == 0) l = 0.5;
            else {
                l = cos((double)(a * j) * M_PI / n);
                if (j == 50) l *= 0.5;
            }
            acc += l * (2.0 / n) * w;
        }
        ws[WS_CCW + j] = (float)acc;
    }
}

// Build transposed weights WT[k][j] (contiguous j -> s_load_dwordx16 streams).
__global__ void k_wt(const float* __restrict__ f1W0, const float* __restrict__ f1W1,
                     const float* __restrict__ f1W2,
                     const float* __restrict__ f2W0, const float* __restrict__ f2W1,
                     const float* __restrict__ f2W2, float* __restrict__ wt) {
    int t = blockIdx.x * 256 + threadIdx.x;
    if (t < 320) {
        int i = t >> 6, j = t & 63;
        wt[t]          = f1W0[j * 5 + i];
        wt[WT_NET + t] = f2W0[j * 5 + i];
    }
    if (t < 4096) {
        int k = t >> 6, j = t & 63;
        wt[WT_W1 + t]          = f1W1[j * 64 + k];
        wt[WT_W2 + t]          = f1W2[j * 64 + k];
        wt[WT_NET + WT_W1 + t] = f2W1[j * 64 + k];
        wt[WT_NET + WT_W2 + t] = f2W2[j * 64 + k];
    }
}

// xm[b] = dot(x_[b,:], log_weight)  — one wave per row
__global__ void k_xm(const float* __restrict__ x_, const float* __restrict__ lw,
                     float* __restrict__ xm) {
    int row  = (blockIdx.x * blockDim.x + threadIdx.x) >> 6;
    int lane = threadIdx.x & 63;
    if (row >= BB) return;
    float v = 0.0f;
    for (int i = lane; i < 100; i += 64) v = fmaf(x_[row * 100 + i], lw[i], v);
    #pragma unroll
    for (int off = 32; off > 0; off >>= 1) v += __shfl_xor(v, off, 64);
    if (lane == 0) xm[row] = v;
}

// x = (1-lam)*xm + lam*I1 ; x2 = (1-lam)*xm + lam*I2 ; per-block max(x2)
__global__ void k_pre(const float* __restrict__ xm, const float* __restrict__ out,
                      const float* __restrict__ ws_lam,
                      float* __restrict__ x, float* __restrict__ x2,
                      float* __restrict__ pmax, int first) {
    int b = blockIdx.x * 256 + threadIdx.x;
    float lam = ws_lam[0];
    float i1 = first ? 0.0f : out[b];
    float i2 = first ? 0.0f : out[2 * BB + b];
    float m  = xm[b];
    float xv  = (1.0f - lam) * m + lam * i1;
    float x2v = (1.0f - lam) * m + lam * i2;
    x[b] = xv;
    x2[b] = x2v;
    __shared__ float red[256];
    red[threadIdx.x] = x2v;
    __syncthreads();
    #pragma unroll
    for (int off = 128; off > 0; off >>= 1) {
        if (threadIdx.x < off)
            red[threadIdx.x] = fmaxf(red[threadIdx.x], red[threadIdx.x + off]);
        __syncthreads();
    }
    if (threadIdx.x == 0) pmax[blockIdx.x] = red[0];
}

// Blocks [0,NBI): I1 quadrature (f1, 0 -> x).  [NBI,2*NBI): I2 (f2, x2 -> xmax).
// [2*NBI, +NBF): out_first = f1(x2, h).
// MLP strategy: acc[64] static registers (one per output feature); k-loop rolled;
// weight COLUMNS streamed via scalar loads (uniform addr); activations bounce
// through a per-thread-private LDS column (f16 packed) -> compact I$-resident code.
__global__ __launch_bounds__(256) void k_int(
    const float* __restrict__ xarr, const float* __restrict__ x2arr,
    const float* __restrict__ pmax, const float* __restrict__ h_,
    const float* __restrict__ ccw, const float* __restrict__ ccs,
    const float* __restrict__ wt,
    const float* __restrict__ f1b0, const float* __restrict__ f1b1,
    const float* __restrict__ f1b2, const float* __restrict__ f1W3,
    const float* __restrict__ f1b3, const float* __restrict__ f1Wf,
    const float* __restrict__ f2b0, const float* __restrict__ f2b1,
    const float* __restrict__ f2b2, const float* __restrict__ f2W3,
    const float* __restrict__ f2b3, const float* __restrict__ f2Wf,
    float* __restrict__ out)
{
    __shared__ unsigned act[32][256];   // f16x2 hidden activations, column-private
    __shared__ float red[256];

    const int blk = blockIdx.x;
    const int tid = threadIdx.x;
    int kind, b_base = 0, b, s = 0;
    if (blk < NBI)            { kind = 0; b_base = blk * TBR; }
    else if (blk < 2 * NBI)   { kind = 1; b_base = (blk - NBI) * TBR; }
    else                      { kind = 2; }

    float xmax = 0.0f, xin;
    if (kind == 2) {
        b = (blk - 2 * NBI) * 256 + tid;       // exactly covers 4096
        xin = x2arr[b];
    } else {
        if (kind == 1) {
            float m = pmax[0];
            #pragma unroll
            for (int i = 1; i < 16; ++i) m = fmaxf(m, pmax[i]);
            xmax = m + 10.0f;
        }
        int lb = tid / 51;                      // 0..5 (tid=255 -> 5, padding lane)
        s = tid - lb * 51;
        b = b_base + (lb < TBR - 1 ? lb : TBR - 1);
        if (b > BB - 1) b = BB - 1;             // clamp for last partial block
        float t = (ccs[s] + 1.0f) * 0.5f;
        if (kind == 0) xin = xarr[b] * t;                         // x0 = 0
        else { float x0v = x2arr[b]; xin = x0v + (xmax - x0v) * t; }
    }
    const float4 h4 = ((const float4*)h_)[b];

    const bool u2 = (kind == 1);
    const float* WT = wt + (u2 ? WT_NET : 0);
    const float* B0 = u2 ? f2b0 : f1b0;
    const float* B1 = u2 ? f2b1 : f1b1;
    const float* B2 = u2 ? f2b2 : f1b2;
    const float* W3 = u2 ? f2W3 : f1W3;
    const float* B3 = u2 ? f2b3 : f1b3;
    const float* WF = u2 ? f2Wf : f1Wf;
    const float p0 = u2 ? 1.5f : 1.1f;
    const float p1 = u2 ? 2.0f : 1.1f;
    const float p2 = u2 ? 2.5f : 1.5f;
    const float p3 = u2 ? 3.0f : 2.0f;
    const float p4 = u2 ? 3.5f : 2.5f;

    float acc[64];

    // ---- layer 0: 5 -> 64 (inputs in registers) ----
    #pragma unroll
    for (int j = 0; j < 64; ++j) acc[j] = B0[j];
    const float in5[5] = { xin, h4.x, h4.y, h4.z, h4.w };
    #pragma unroll
    for (int i = 0; i < 5; ++i) {
        const float* w = WT + i * 64;
        const float v = in5[i];
        #pragma unroll
        for (int j = 0; j < 64; ++j) acc[j] = fmaf(w[j], v, acc[j]);
    }
    #pragma unroll
    for (int j = 0; j < 32; ++j) {
        unsigned short u0 = __half_as_ushort(__float2half_rn(fmaxf(acc[2*j],   0.0f)));
        unsigned short u1 = __half_as_ushort(__float2half_rn(fmaxf(acc[2*j+1], 0.0f)));
        act[j][tid] = (unsigned)u0 | ((unsigned)u1 << 16);
    }

    // ---- layer 1: 64 -> 64 ----
    #pragma unroll
    for (int j = 0; j < 64; ++j) acc[j] = B1[j];
    {
        const float* WL = WT + WT_W1;
        #pragma clang loop unroll(disable)
        for (int kk = 0; kk < 32; ++kk) {
            const unsigned pv = act[kk][tid];
            const float a0 = __half2float(__ushort_as_half((unsigned short)(pv & 0xffffu)));
            const float a1 = __half2float(__ushort_as_half((unsigned short)(pv >> 16)));
            const float* w0 = WL + (2 * kk) * 64;
            const float* w1 = w0 + 64;
            #pragma unroll
            for (int j = 0; j < 64; ++j)
                acc[j] = fmaf(w0[j], a0, fmaf(w1[j], a1, acc[j]));
        }
    }
    #pragma unroll
    for (int j = 0; j < 32; ++j) {
        unsigned short u0 = __half_as_ushort(__float2half_rn(fmaxf(acc[2*j],   0.0f)));
        unsigned short u1 = __half_as_ushort(__float2half_rn(fmaxf(acc[2*j+1], 0.0f)));
        act[j][tid] = (unsigned)u0 | ((unsigned)u1 << 16);
    }

    // ---- layer 2: 64 -> 64 ----
    #pragma unroll
    for (int j = 0; j < 64; ++j) acc[j] = B2[j];
    {
        const float* WL = WT + WT_W2;
        #pragma clang loop unroll(disable)
        for (int kk = 0; kk < 32; ++kk) {
            const unsigned pv = act[kk][tid];
            const float a0 = __half2float(__ushort_as_half((unsigned short)(pv & 0xffffu)));
            const float a1 = __half2float(__ushort_as_half((unsigned short)(pv >> 16)));
            const float* w0 = WL + (2 * kk) * 64;
            const float* w1 = w0 + 64;
            #pragma unroll
            for (int j = 0; j < 64; ++j)
                acc[j] = fmaf(w0[j], a0, fmaf(w1[j], a1, acc[j]));
        }
    }

    // ---- layer 3: 64 -> 1 (relu fused) + epilogue ----
    float y = B3[0];
    #pragma unroll
    for (int k = 0; k < 64; ++k) y = fmaf(W3[k], fmaxf(acc[k], 0.0f), y);
    if (y <= 0.0f) y = __expf(y) - 1.0f;   // elu
    float z = y + 1.0f;                    // z >= 0
    float lg = __logf(z);                  // z=0 -> -inf -> exp -> 0 (matches 0**p)
    float g = WF[0] / (__expf(p0 * lg) + 1.0f)
            + WF[1] / (__expf(p1 * lg) + 1.0f)
            + WF[2] / (__expf(p2 * lg) + 1.0f)
            + WF[3] / (__expf(p3 * lg) + 1.0f)
            + WF[4] / (__expf(p4 * lg) + 1.0f);
    float val = fmaxf(g, 0.0f);

    if (kind == 2) { out[BB + b] = val; return; }   // whole block returns together

    red[tid] = ccw[s] * val;
    __syncthreads();
    if (tid < TBR) {
        float sum = 0.0f;
        for (int i = 0; i < NS; ++i) sum += red[tid * NS + i];
        int bo = b_base + tid;
        if (bo < BB) {
            if (kind == 0) out[bo] = sum * xarr[bo] * 0.5f;
            else out[2 * BB + bo] = sum * (xmax - x2arr[bo]) * 0.5f * INV_ALPHA;
        }
    }
}

extern "C" void kernel_launch(void* const* d_in, const int* in_sizes, int n_in,
                              void* d_out, int out_size, void* d_ws, size_t ws_size,
                              hipStream_t stream) {
    const float* x_  = (const float*)d_in[0];
    const float* h_  = (const float*)d_in[1];
    const float* lw  = (const float*)d_in[2];
    const float* sp  = (const float*)d_in[3];
    const float* f1W0 = (const float*)d_in[4];   const float* f1b0 = (const float*)d_in[5];
    const float* f1W1 = (const float*)d_in[6];   const float* f1b1 = (const float*)d_in[7];
    const float* f1W2 = (const float*)d_in[8];   const float* f1b2 = (const float*)d_in[9];
    const float* f1W3 = (const float*)d_in[10];  const float* f1b3 = (const float*)d_in[11];
    const float* f1Wf = (const float*)d_in[12];
    const float* f2W0 = (const float*)d_in[13];  const float* f2b0 = (const float*)d_in[14];
    const float* f2W1 = (const float*)d_in[15];  const float* f2b1 = (const float*)d_in[16];
    const float* f2W2 = (const float*)d_in[17];  const float* f2b2 = (const float*)d_in[18];
    const float* f2W3 = (const float*)d_in[19];  const float* f2b3 = (const float*)d_in[20];
    const float* f2Wf = (const float*)d_in[21];
    float* out = (float*)d_out;
    float* ws  = (float*)d_ws;

    k_init<<<1, 64, 0, stream>>>(sp, ws);
    k_wt<<<16, 256, 0, stream>>>(f1W0, f1W1, f1W2, f2W0, f2W1, f2W2, ws + WS_WT);
    k_xm<<<(BB * 64) / 256, 256, 0, stream>>>(x_, lw, ws + WS_XM);

    for (int step = 0; step < 2; ++step) {
        k_pre<<<16, 256, 0, stream>>>(ws + WS_XM, out, ws + WS_LAM,
                                      ws + WS_X, ws + WS_X2, ws + WS_PMAX,
                                      step == 0 ? 1 : 0);
        k_int<<<GRID_INT, 256, 0, stream>>>(
            ws + WS_X, ws + WS_X2, ws + WS_PMAX, h_,
            ws + WS_CCW, ws + WS_CCS, ws + WS_WT,
            f1b0, f1b1, f1b2, f1W3, f1b3, f1Wf,
            f2b0, f2b1, f2b2, f2W3, f2b3, f2Wf,
            out);
    }
}

// Round 3
// 176.866 us; speedup vs baseline: 2.6828x; 1.7754x over previous
//
#include <hip/hip_runtime.h>
#include <math.h>

typedef _Float16 half8v __attribute__((ext_vector_type(8)));
typedef _Float16 half4v __attribute__((ext_vector_type(4)));
typedef float float4v __attribute__((ext_vector_type(4)));

// ---- problem constants ----
#define BB    4096      // batch
#define NS    51        // NB_STEPS+1 quadrature points
#define TBR   5         // batch rows per integrate block (5*51=255 of 256 threads)
#define NBI   820       // ceil(4096/5) blocks per integral
#define NBF   16        // blocks for out_first (4096/256)
#define GRID_INT (2*NBI + NBF)
#define INV_ALPHA (1.0f/0.9f)
#define AROW  72        // act row stride in halfs (144B: 16B-aligned, even bank spread)

// ---- workspace float offsets ----
#define WS_CCW  0
#define WS_CCS  64
#define WS_LAM  128
#define WS_PMAX 160
#define WS_XM   256
#define WS_X    (WS_XM + BB)
#define WS_X2   (WS_X + BB)
#define WS_W0T  16384              // f32 W0 transposed: f1 320 floats, f2 at +320
#define WS_WH   17024              // f16 hidden weights, 4*4096 halfs (16B-aligned)

// Clenshaw-Curtis weights/steps + lambda, computed in double to match numpy.
__global__ void k_init(const float* __restrict__ sp, float* __restrict__ ws) {
    int j = threadIdx.x;
    if (j == 0) ws[WS_LAM] = 1.0f / (1.0f + expf(-sp[0]));
    if (j <= 50) {
        const double n = 50.0;
        ws[WS_CCS + j] = (float)cos((double)j * M_PI / n);
        double acc = 0.0;
        for (int a = 0; a <= 50; ++a) {
            double w;
            if (a == 0) w = 1.0;
            else if ((a & 1) == 0) w = 2.0 / (1.0 - (double)a * (double)a);
            else w = 0.0;
            double l;
            if (j == 0) l = 0.5;
            else {
                l = cos((double)(a * j) * M_PI / n);
                if (j == 50) l *= 0.5;
            }
            acc += l * (2.0 / n) * w;
        }
        ws[WS_CCW + j] = (float)acc;
    }
}

// W0 transposed (f32) + hidden weights cast to f16 in ORIGINAL [j][k] layout
// (that layout is exactly the MFMA A-operand layout: 8 contiguous k per lane).
__global__ void k_wt(const float* __restrict__ f1W0, const float* __restrict__ f1W1,
                     const float* __restrict__ f1W2,
                     const float* __restrict__ f2W0, const float* __restrict__ f2W1,
                     const float* __restrict__ f2W2,
                     float* __restrict__ w0t, _Float16* __restrict__ wh) {
    int t = blockIdx.x * 256 + threadIdx.x;
    if (t < 320) {
        int i = t >> 6, j = t & 63;
        w0t[t]       = f1W0[j * 5 + i];
        w0t[320 + t] = f2W0[j * 5 + i];
    }
    if (t < 4096) {
        wh[t]         = (_Float16)f1W1[t];
        wh[4096 + t]  = (_Float16)f1W2[t];
        wh[8192 + t]  = (_Float16)f2W1[t];
        wh[12288 + t] = (_Float16)f2W2[t];
    }
}

// xm[b] = dot(x_[b,:], log_weight)  — one wave per row
__global__ void k_xm(const float* __restrict__ x_, const float* __restrict__ lw,
                     float* __restrict__ xm) {
    int row  = (blockIdx.x * blockDim.x + threadIdx.x) >> 6;
    int lane = threadIdx.x & 63;
    if (row >= BB) return;
    float v = 0.0f;
    for (int i = lane; i < 100; i += 64) v = fmaf(x_[row * 100 + i], lw[i], v);
    #pragma unroll
    for (int off = 32; off > 0; off >>= 1) v += __shfl_xor(v, off, 64);
    if (lane == 0) xm[row] = v;
}

// x = (1-lam)*xm + lam*I1 ; x2 = (1-lam)*xm + lam*I2 ; per-block max(x2)
__global__ void k_pre(const float* __restrict__ xm, const float* __restrict__ out,
                      const float* __restrict__ ws_lam,
                      float* __restrict__ x, float* __restrict__ x2,
                      float* __restrict__ pmax, int first) {
    int b = blockIdx.x * 256 + threadIdx.x;
    float lam = ws_lam[0];
    float i1 = first ? 0.0f : out[b];
    float i2 = first ? 0.0f : out[2 * BB + b];
    float m  = xm[b];
    float xv  = (1.0f - lam) * m + lam * i1;
    float x2v = (1.0f - lam) * m + lam * i2;
    x[b] = xv;
    x2[b] = x2v;
    __shared__ float red[256];
    red[threadIdx.x] = x2v;
    __syncthreads();
    #pragma unroll
    for (int off = 128; off > 0; off >>= 1) {
        if (threadIdx.x < off)
            red[threadIdx.x] = fmaxf(red[threadIdx.x], red[threadIdx.x + off]);
        __syncthreads();
    }
    if (threadIdx.x == 0) pmax[blockIdx.x] = red[0];
}

// One 64->64 hidden layer via MFMA 16x16x32_f16.
// Computes OUT^T = W * ACT^T:  A = W[j][k] (global f16, row-major = A-op layout),
// B = ACT^T (act[row][k] f16 rows in LDS), D[m=j][n=row].
// Each wave owns rows [64w, 64w+64) -> no cross-wave LDS sharing, no barrier.
__device__ __forceinline__ void mfma_layer(
    const _Float16* __restrict__ Wg, const float* __restrict__ Bg,
    _Float16* act, int tid)
{
    const int lane  = tid & 63;
    const int wbase = tid & 192;         // wave row base (64 * wave_id)
    const int lo    = lane & 15;
    const int quad  = lane >> 4;         // 0..3

    half8v Af[4][2];
    #pragma unroll
    for (int m = 0; m < 4; ++m)
        #pragma unroll
        for (int kb = 0; kb < 2; ++kb)
            Af[m][kb] = *(const half8v*)(Wg + (16 * m + lo) * 64 + 32 * kb + quad * 8);

    float4v bb[4];
    #pragma unroll
    for (int m = 0; m < 4; ++m)
        bb[m] = *(const float4v*)(Bg + 16 * m + quad * 4);

    half8v Bf[4][2];
    #pragma unroll
    for (int n = 0; n < 4; ++n)
        #pragma unroll
        for (int kb = 0; kb < 2; ++kb)
            Bf[n][kb] = *(const half8v*)(act + (wbase + 16 * n + lo) * AROW + 32 * kb + quad * 8);

    float4v accv[4][4];
    #pragma unroll
    for (int m = 0; m < 4; ++m)
        #pragma unroll
        for (int n = 0; n < 4; ++n) {
            float4v c = bb[m];
            c = __builtin_amdgcn_mfma_f32_16x16x32_f16(Af[m][0], Bf[n][0], c, 0, 0, 0);
            c = __builtin_amdgcn_mfma_f32_16x16x32_f16(Af[m][1], Bf[n][1], c, 0, 0, 0);
            accv[m][n] = c;
        }

    // relu -> f16 -> back to act rows (4 consecutive j per lane -> one b64 store)
    #pragma unroll
    for (int m = 0; m < 4; ++m)
        #pragma unroll
        for (int n = 0; n < 4; ++n) {
            float4v c = accv[m][n];
            half4v o;
            o[0] = (_Float16)fmaxf(c[0], 0.0f);
            o[1] = (_Float16)fmaxf(c[1], 0.0f);
            o[2] = (_Float16)fmaxf(c[2], 0.0f);
            o[3] = (_Float16)fmaxf(c[3], 0.0f);
            int row = wbase + 16 * n + lo;
            *(half4v*)(act + row * AROW + 16 * m + quad * 4) = o;
        }
}

// Blocks [0,NBI): I1 quadrature (f1, 0 -> x).  [NBI,2*NBI): I2 (f2, x2 -> xmax).
// [2*NBI, +NBF): out_first = f1(x2, h).
__global__ __launch_bounds__(256) void k_int(
    const float* __restrict__ xarr, const float* __restrict__ x2arr,
    const float* __restrict__ pmax, const float* __restrict__ h_,
    const float* __restrict__ ccw, const float* __restrict__ ccs,
    const float* __restrict__ w0t, const _Float16* __restrict__ wh,
    const float* __restrict__ f1b0, const float* __restrict__ f1b1,
    const float* __restrict__ f1b2, const float* __restrict__ f1W3,
    const float* __restrict__ f1b3, const float* __restrict__ f1Wf,
    const float* __restrict__ f2b0, const float* __restrict__ f2b1,
    const float* __restrict__ f2b2, const float* __restrict__ f2W3,
    const float* __restrict__ f2b3, const float* __restrict__ f2Wf,
    float* __restrict__ out)
{
    __shared__ _Float16 act[256 * AROW];   // [row][k] f16, row stride 72 (144B)
    __shared__ float red[256];

    const int blk = blockIdx.x;
    const int tid = threadIdx.x;
    int kind, b_base = 0, b, s = 0;
    if (blk < NBI)            { kind = 0; b_base = blk * TBR; }
    else if (blk < 2 * NBI)   { kind = 1; b_base = (blk - NBI) * TBR; }
    else                      { kind = 2; }

    float xmax = 0.0f, xin;
    if (kind == 2) {
        b = (blk - 2 * NBI) * 256 + tid;       // exactly covers 4096
        xin = x2arr[b];
    } else {
        if (kind == 1) {
            float m = pmax[0];
            #pragma unroll
            for (int i = 1; i < 16; ++i) m = fmaxf(m, pmax[i]);
            xmax = m + 10.0f;
        }
        int lb = tid / 51;                      // 0..5 (tid=255 -> 5, padding lane)
        s = tid - lb * 51;
        b = b_base + (lb < TBR - 1 ? lb : TBR - 1);
        if (b > BB - 1) b = BB - 1;             // clamp for last partial block
        float t = (ccs[s] + 1.0f) * 0.5f;
        if (kind == 0) xin = xarr[b] * t;                         // x0 = 0
        else { float x0v = x2arr[b]; xin = x0v + (xmax - x0v) * t; }
    }
    const float4 h4 = ((const float4*)h_)[b];

    const bool u2 = (kind == 1);
    const float* W0T = w0t + (u2 ? 320 : 0);
    const _Float16* W1h = wh + (u2 ? 8192 : 0);
    const _Float16* W2h = W1h + 4096;
    const float* B0 = u2 ? f2b0 : f1b0;
    const float* B1 = u2 ? f2b1 : f1b1;
    const float* B2 = u2 ? f2b2 : f1b2;
    const float* W3 = u2 ? f2W3 : f1W3;
    const float* B3 = u2 ? f2b3 : f1b3;
    const float* WF = u2 ? f2Wf : f1Wf;
    const float p0 = u2 ? 1.5f : 1.1f;
    const float p1 = u2 ? 2.0f : 1.1f;
    const float p2 = u2 ? 2.5f : 1.5f;
    const float p3 = u2 ? 3.0f : 2.0f;
    const float p4 = u2 ? 3.5f : 2.5f;

    // ---- layer 0: 5 -> 64, per-thread VALU (weights via wave-uniform s_loads) ----
    {
        float a0[64];
        #pragma unroll
        for (int j = 0; j < 64; ++j) a0[j] = B0[j];
        const float in5[5] = { xin, h4.x, h4.y, h4.z, h4.w };
        #pragma unroll
        for (int i = 0; i < 5; ++i) {
            const float* w = W0T + i * 64;
            const float v = in5[i];
            #pragma unroll
            for (int j = 0; j < 64; ++j) a0[j] = fmaf(w[j], v, a0[j]);
        }
        _Float16* myrow = act + tid * AROW;
        #pragma unroll
        for (int g = 0; g < 8; ++g) {
            half8v h;
            #pragma unroll
            for (int e = 0; e < 8; ++e) h[e] = (_Float16)fmaxf(a0[8 * g + e], 0.0f);
            *(half8v*)(myrow + 8 * g) = h;
        }
    }

    // ---- hidden layers via MFMA (per-wave tiles; per-wave DS is in-order) ----
    mfma_layer(W1h, B1, act, tid);
    mfma_layer(W2h, B2, act, tid);

    // ---- layer 3: 64 -> 1 (relu already applied by mfma_layer) + epilogue ----
    float y = B3[0];
    {
        const _Float16* myrow = act + tid * AROW;
        #pragma unroll
        for (int g = 0; g < 8; ++g) {
            half8v h = *(const half8v*)(myrow + 8 * g);
            #pragma unroll
            for (int e = 0; e < 8; ++e) y = fmaf(W3[8 * g + e], (float)h[e], y);
        }
    }
    if (y <= 0.0f) y = __expf(y) - 1.0f;   // elu
    float z = y + 1.0f;                    // z >= 0
    float lg = __logf(z);                  // z=0 -> -inf -> exp -> 0 (matches 0**p)
    float g = WF[0] / (__expf(p0 * lg) + 1.0f)
            + WF[1] / (__expf(p1 * lg) + 1.0f)
            + WF[2] / (__expf(p2 * lg) + 1.0f)
            + WF[3] / (__expf(p3 * lg) + 1.0f)
            + WF[4] / (__expf(p4 * lg) + 1.0f);
    float val = fmaxf(g, 0.0f);

    if (kind == 2) { out[BB + b] = val; return; }   // whole block returns together

    red[tid] = ccw[s] * val;
    __syncthreads();
    if (tid < TBR) {
        float sum = 0.0f;
        for (int i = 0; i < NS; ++i) sum += red[tid * NS + i];
        int bo = b_base + tid;
        if (bo < BB) {
            if (kind == 0) out[bo] = sum * xarr[bo] * 0.5f;
            else out[2 * BB + bo] = sum * (xmax - x2arr[bo]) * 0.5f * INV_ALPHA;
        }
    }
}

extern "C" void kernel_launch(void* const* d_in, const int* in_sizes, int n_in,
                              void* d_out, int out_size, void* d_ws, size_t ws_size,
                              hipStream_t stream) {
    const float* x_  = (const float*)d_in[0];
    const float* h_  = (const float*)d_in[1];
    const float* lw  = (const float*)d_in[2];
    const float* sp  = (const float*)d_in[3];
    const float* f1W0 = (const float*)d_in[4];   const float* f1b0 = (const float*)d_in[5];
    const float* f1W1 = (const float*)d_in[6];   const float* f1b1 = (const float*)d_in[7];
    const float* f1W2 = (const float*)d_in[8];   const float* f1b2 = (const float*)d_in[9];
    const float* f1W3 = (const float*)d_in[10];  const float* f1b3 = (const float*)d_in[11];
    const float* f1Wf = (const float*)d_in[12];
    const float* f2W0 = (const float*)d_in[13];  const float* f2b0 = (const float*)d_in[14];
    const float* f2W1 = (const float*)d_in[15];  const float* f2b1 = (const float*)d_in[16];
    const float* f2W2 = (const float*)d_in[17];  const float* f2b2 = (const float*)d_in[18];
    const float* f2W3 = (const float*)d_in[19];  const float* f2b3 = (const float*)d_in[20];
    const float* f2Wf = (const float*)d_in[21];
    float* out = (float*)d_out;
    float* ws  = (float*)d_ws;

    k_init<<<1, 64, 0, stream>>>(sp, ws);
    k_wt<<<16, 256, 0, stream>>>(f1W0, f1W1, f1W2, f2W0, f2W1, f2W2,
                                 ws + WS_W0T, (_Float16*)(ws + WS_WH));
    k_xm<<<(BB * 64) / 256, 256, 0, stream>>>(x_, lw, ws + WS_XM);

    for (int step = 0; step < 2; ++step) {
        k_pre<<<16, 256, 0, stream>>>(ws + WS_XM, out, ws + WS_LAM,
                                      ws + WS_X, ws + WS_X2, ws + WS_PMAX,
                                      step == 0 ? 1 : 0);
        k_int<<<GRID_INT, 256, 0, stream>>>(
            ws + WS_X, ws + WS_X2, ws + WS_PMAX, h_,
            ws + WS_CCW, ws + WS_CCS, ws + WS_W0T, (const _Float16*)(ws + WS_WH),
            f1b0, f1b1, f1b2, f1W3, f1b3, f1Wf,
            f2b0, f2b1, f2b2, f2W3, f2b3, f2Wf,
            out);
    }
}

// Round 4
// 164.974 us; speedup vs baseline: 2.8762x; 1.0721x over previous
//
#include <hip/hip_runtime.h>
#include <math.h>

typedef _Float16 half8v __attribute__((ext_vector_type(8)));
typedef _Float16 half4v __attribute__((ext_vector_type(4)));
typedef _Float16 half2v __attribute__((ext_vector_type(2)));
typedef float float4v __attribute__((ext_vector_type(4)));

// ---- problem constants ----
#define BB    4096
#define NS    51
#define TBR   5         // batch rows per integrate block (5*51=255 of 256 threads)
#define NBI   820       // ceil(4096/5)
#define NBF   16
#define GRID_INT (2*NBI + NBF)
#define INV_ALPHA (1.0f/0.9f)
#define AROW  72        // act row stride in halfs (144B)

// ---- workspace float offsets ----
#define WS_CCW  0
#define WS_CCS  64
#define WS_LAM  128
#define WS_PM16 160
#define WS_PM64 192
#define WS_XM   256
#define WS_X    (WS_XM + BB)
#define WS_X2   (WS_X + BB)
#define WS_H    12544          // halfs region starts at byte 50176 (16B aligned)
// half offsets within WS_H
#define H_NET   8192           // per-net stride for W1+W2
#define H_W2    4096
#define H_W0    16384          // + net*2048 : [64 j][32 k] zero-padded
#define H_W3    20480          // + net*64

// ---- fused setup: xm + partial maxes | weight repack | CC weights + lam ----
__global__ void k_setup(const float* __restrict__ x_, const float* __restrict__ lw,
                        const float* __restrict__ sp,
                        const float* __restrict__ f1W0, const float* __restrict__ f1W1,
                        const float* __restrict__ f1W2, const float* __restrict__ f1W3,
                        const float* __restrict__ f2W0, const float* __restrict__ f2W1,
                        const float* __restrict__ f2W2, const float* __restrict__ f2W3,
                        float* __restrict__ ws) {
    _Float16* wh = (_Float16*)(ws + WS_H);
    const int blk = blockIdx.x, tid = threadIdx.x;
    if (blk < 64) {
        // 64 rows of xm per block (wave w: rows blk*64 + w*16 + r), + block max
        int wave = tid >> 6, lane = tid & 63;
        float vmax = -1e30f;
        for (int r = 0; r < 16; ++r) {
            int row = blk * 64 + wave * 16 + r;
            float v = 0.0f;
            for (int i = lane; i < 100; i += 64) v = fmaf(x_[row * 100 + i], lw[i], v);
            #pragma unroll
            for (int off = 32; off > 0; off >>= 1) v += __shfl_xor(v, off, 64);
            if (lane == 0) ws[WS_XM + row] = v;
            vmax = fmaxf(vmax, v);
        }
        __shared__ float sm[4];
        if (lane == 0) sm[wave] = vmax;
        __syncthreads();
        if (tid == 0)
            ws[WS_PM64 + blk] = fmaxf(fmaxf(sm[0], sm[1]), fmaxf(sm[2], sm[3]));
    } else if (blk < 80) {
        int t = (blk - 64) * 256 + tid;        // 0..4095
        wh[t]               = (_Float16)f1W1[t];
        wh[H_W2 + t]        = (_Float16)f1W2[t];
        wh[H_NET + t]       = (_Float16)f2W1[t];
        wh[H_NET + H_W2 + t] = (_Float16)f2W2[t];
        if (t < 2048) {
            int j = t >> 5, k = t & 31;        // W0 padded to K=32 (A-operand layout)
            wh[H_W0 + t]        = (k < 5) ? (_Float16)f1W0[j * 5 + k] : (_Float16)0.0f;
            wh[H_W0 + 2048 + t] = (k < 5) ? (_Float16)f2W0[j * 5 + k] : (_Float16)0.0f;
        }
        if (t < 64) {
            wh[H_W3 + t]      = (_Float16)f1W3[t];
            wh[H_W3 + 64 + t] = (_Float16)f2W3[t];
        }
    } else {
        if (tid == 60) ws[WS_LAM] = 1.0f / (1.0f + expf(-sp[0]));
        if (tid <= 50) {
            ws[WS_CCS + tid] = cospif((float)tid / 50.0f);
            float acc = 0.0f;
            for (int a = 0; a <= 50; ++a) {
                float w;
                if (a == 0) w = 1.0f;
                else if ((a & 1) == 0) w = 2.0f / (1.0f - (float)(a * a));
                else continue;
                float l;
                if (tid == 0) l = 0.5f;
                else {
                    int m = (a * tid) % 100;   // exact period reduction
                    l = cospif((float)m / 50.0f);
                    if (tid == 50) l *= 0.5f;
                }
                acc += l * 0.04f * w;          // 2/n = 0.04
            }
            ws[WS_CCW + tid] = acc;
        }
    }
}

// x/x2 for RNN step 1 + 16 partial maxes of x2
__global__ void k_pre(const float* __restrict__ xm, const float* __restrict__ out,
                      const float* __restrict__ ws_lam,
                      float* __restrict__ x, float* __restrict__ x2,
                      float* __restrict__ pmax) {
    int b = blockIdx.x * 256 + threadIdx.x;
    float lam = ws_lam[0];
    float m = xm[b];
    float xv  = (1.0f - lam) * m + lam * out[b];
    float x2v = (1.0f - lam) * m + lam * out[2 * BB + b];
    x[b] = xv;
    x2[b] = x2v;
    __shared__ float red[256];
    red[threadIdx.x] = x2v;
    __syncthreads();
    #pragma unroll
    for (int off = 128; off > 0; off >>= 1) {
        if (threadIdx.x < off)
            red[threadIdx.x] = fmaxf(red[threadIdx.x], red[threadIdx.x + off]);
        __syncthreads();
    }
    if (threadIdx.x == 0) pmax[blockIdx.x] = red[0];
}

// hidden layer 64->64: OUT^T = W*ACT^T, per-wave 64-row tile, barrier-free.
__device__ __forceinline__ void mfma_hidden(
    const _Float16* __restrict__ Wg, const float* __restrict__ Bg,
    _Float16* act, int tid)
{
    const int lane = tid & 63, wbase = tid & 192;
    const int lo = lane & 15, quad = lane >> 4;
    half8v Af[4][2];
    #pragma unroll
    for (int m = 0; m < 4; ++m)
        #pragma unroll
        for (int kb = 0; kb < 2; ++kb)
            Af[m][kb] = *(const half8v*)(Wg + (16 * m + lo) * 64 + 32 * kb + quad * 8);
    float4v bb[4];
    #pragma unroll
    for (int m = 0; m < 4; ++m) bb[m] = *(const float4v*)(Bg + 16 * m + quad * 4);
    half8v Bf[4][2];
    #pragma unroll
    for (int n = 0; n < 4; ++n)
        #pragma unroll
        for (int kb = 0; kb < 2; ++kb)
            Bf[n][kb] = *(const half8v*)(act + (wbase + 16 * n + lo) * AROW + 32 * kb + quad * 8);
    float4v accv[4][4];
    #pragma unroll
    for (int m = 0; m < 4; ++m)
        #pragma unroll
        for (int n = 0; n < 4; ++n) {
            float4v c = bb[m];
            c = __builtin_amdgcn_mfma_f32_16x16x32_f16(Af[m][0], Bf[n][0], c, 0, 0, 0);
            c = __builtin_amdgcn_mfma_f32_16x16x32_f16(Af[m][1], Bf[n][1], c, 0, 0, 0);
            accv[m][n] = c;
        }
    #pragma unroll
    for (int m = 0; m < 4; ++m)
        #pragma unroll
        for (int n = 0; n < 4; ++n) {
            float4v c = accv[m][n];
            half4v o;
            o[0] = (_Float16)fmaxf(c[0], 0.0f); o[1] = (_Float16)fmaxf(c[1], 0.0f);
            o[2] = (_Float16)fmaxf(c[2], 0.0f); o[3] = (_Float16)fmaxf(c[3], 0.0f);
            *(half4v*)(act + (wbase + 16 * n + lo) * AROW + 16 * m + quad * 4) = o;
        }
}

// first layer 5(->pad 32)->64 via single-K-block MFMA
__device__ __forceinline__ void mfma_first(
    const _Float16* __restrict__ Wg, const float* __restrict__ Bg,
    _Float16* act, int tid)
{
    const int lane = tid & 63, wbase = tid & 192;
    const int lo = lane & 15, quad = lane >> 4;
    half8v Af[4];
    #pragma unroll
    for (int m = 0; m < 4; ++m)
        Af[m] = *(const half8v*)(Wg + (16 * m + lo) * 32 + quad * 8);
    float4v bb[4];
    #pragma unroll
    for (int m = 0; m < 4; ++m) bb[m] = *(const float4v*)(Bg + 16 * m + quad * 4);
    half8v Bf[4];
    #pragma unroll
    for (int n = 0; n < 4; ++n)
        Bf[n] = *(const half8v*)(act + (wbase + 16 * n + lo) * AROW + quad * 8);
    float4v accv[4][4];
    #pragma unroll
    for (int m = 0; m < 4; ++m)
        #pragma unroll
        for (int n = 0; n < 4; ++n)
            accv[m][n] = __builtin_amdgcn_mfma_f32_16x16x32_f16(Af[m], Bf[n], bb[m], 0, 0, 0);
    #pragma unroll
    for (int m = 0; m < 4; ++m)
        #pragma unroll
        for (int n = 0; n < 4; ++n) {
            float4v c = accv[m][n];
            half4v o;
            o[0] = (_Float16)fmaxf(c[0], 0.0f); o[1] = (_Float16)fmaxf(c[1], 0.0f);
            o[2] = (_Float16)fmaxf(c[2], 0.0f); o[3] = (_Float16)fmaxf(c[3], 0.0f);
            *(half4v*)(act + (wbase + 16 * n + lo) * AROW + 16 * m + quad * 4) = o;
        }
}

// Blocks [0,NBI): I1 (f1, 0->x). [NBI,2NBI): I2 (f2, x2->xmax). [2NBI,+NBF): out_first.
// mode 0: step0 — x=x2=(1-lam)*xm inline, xmax from PM64. mode 1: read x/x2/PM16.
__global__ __launch_bounds__(256) void k_int(
    int mode, const float* __restrict__ ws, const float* __restrict__ h_,
    const float* __restrict__ f1b0, const float* __restrict__ f1b1,
    const float* __restrict__ f1b2, const float* __restrict__ f1b3,
    const float* __restrict__ f1Wf,
    const float* __restrict__ f2b0, const float* __restrict__ f2b1,
    const float* __restrict__ f2b2, const float* __restrict__ f2b3,
    const float* __restrict__ f2Wf,
    float* __restrict__ out)
{
    __shared__ _Float16 act[256 * AROW];
    __shared__ float red[256];

    const int blk = blockIdx.x, tid = threadIdx.x;
    const float* xm = ws + WS_XM;
    const float* xarr = ws + WS_X;
    const float* x2arr = ws + WS_X2;
    const _Float16* wh = (const _Float16*)(ws + WS_H);
    const float lam = ws[WS_LAM];
    const float oml = 1.0f - lam;

    int kind, b_base = 0, b, s = 0;
    if (blk < NBI)          { kind = 0; b_base = blk * TBR; }
    else if (blk < 2 * NBI) { kind = 1; b_base = (blk - NBI) * TBR; }
    else                    { kind = 2; }

    float xmax = 0.0f, xin;
    if (kind == 2) {
        b = (blk - 2 * NBI) * 256 + tid;
        xin = mode ? x2arr[b] : oml * xm[b];
    } else {
        if (kind == 1) {
            int lane = tid & 63;
            const float* pm = mode ? (ws + WS_PM16) : (ws + WS_PM64);
            int cnt = mode ? 16 : 64;
            float v = (lane < cnt) ? pm[lane] : -1e30f;
            #pragma unroll
            for (int off = 32; off > 0; off >>= 1) v = fmaxf(v, __shfl_xor(v, off, 64));
            xmax = (mode ? v : oml * v) + 10.0f;
        }
        int lb = tid / 51;
        s = tid - lb * 51;
        b = b_base + (lb < TBR - 1 ? lb : TBR - 1);
        if (b > BB - 1) b = BB - 1;
        float t = (ws[WS_CCS + s] + 1.0f) * 0.5f;
        if (kind == 0) {
            float xb = mode ? xarr[b] : oml * xm[b];
            xin = xb * t;
        } else {
            float x0v = mode ? x2arr[b] : oml * xm[b];
            xin = x0v + (xmax - x0v) * t;
        }
    }
    const float4 h4 = ((const float4*)h_)[b];

    const bool u2 = (kind == 1);
    const _Float16* W0h = wh + H_W0 + (u2 ? 2048 : 0);
    const _Float16* W1h = wh + (u2 ? H_NET : 0);
    const _Float16* W2h = W1h + H_W2;
    const _Float16* W3h = wh + H_W3 + (u2 ? 64 : 0);
    const float* B0 = u2 ? f2b0 : f1b0;
    const float* B1 = u2 ? f2b1 : f1b1;
    const float* B2 = u2 ? f2b2 : f1b2;
    const float* B3 = u2 ? f2b3 : f1b3;
    const float* WF = u2 ? f2Wf : f1Wf;
    const float p0 = u2 ? 1.5f : 1.1f;
    const float p1 = u2 ? 2.0f : 1.1f;
    const float p2 = u2 ? 2.5f : 1.5f;
    const float p3 = u2 ? 3.0f : 2.0f;
    const float p4 = u2 ? 3.5f : 2.5f;

    // stage padded K=32 input row (own row only; per-wave DS in-order -> no barrier)
    {
        _Float16* myrow = act + tid * AROW;
        half8v sv;
        sv[0] = (_Float16)xin; sv[1] = (_Float16)h4.x; sv[2] = (_Float16)h4.y;
        sv[3] = (_Float16)h4.z; sv[4] = (_Float16)h4.w;
        sv[5] = (_Float16)0.0f; sv[6] = (_Float16)0.0f; sv[7] = (_Float16)0.0f;
        half8v zv;
        #pragma unroll
        for (int e = 0; e < 8; ++e) zv[e] = (_Float16)0.0f;
        *(half8v*)(myrow)      = sv;
        *(half8v*)(myrow + 8)  = zv;
        *(half8v*)(myrow + 16) = zv;
        *(half8v*)(myrow + 24) = zv;
    }

    mfma_first (W0h, B0, act, tid);
    mfma_hidden(W1h, B1, act, tid);
    mfma_hidden(W2h, B2, act, tid);

    // final 64->1 dot via v_dot2_f32_f16 + epilogue
    float y = B3[0];
    {
        const _Float16* myrow = act + tid * AROW;
        #pragma unroll
        for (int g = 0; g < 8; ++g) {
            half8v hv = *(const half8v*)(myrow + 8 * g);
            half8v wv = *(const half8v*)(W3h + 8 * g);
            #pragma unroll
            for (int p = 0; p < 4; ++p) {
                half2v a; a[0] = hv[2 * p]; a[1] = hv[2 * p + 1];
                half2v w; w[0] = wv[2 * p]; w[1] = wv[2 * p + 1];
#if defined(__has_builtin) && __has_builtin(__builtin_amdgcn_fdot2)
                y = __builtin_amdgcn_fdot2(a, w, y, false);
#else
                y = fmaf((float)a[0], (float)w[0], y);
                y = fmaf((float)a[1], (float)w[1], y);
#endif
            }
        }
    }
    if (y <= 0.0f) y = __expf(y) - 1.0f;   // elu
    float z = y + 1.0f;
    float lg = __logf(z);
    float g = WF[0] / (__expf(p0 * lg) + 1.0f)
            + WF[1] / (__expf(p1 * lg) + 1.0f)
            + WF[2] / (__expf(p2 * lg) + 1.0f)
            + WF[3] / (__expf(p3 * lg) + 1.0f)
            + WF[4] / (__expf(p4 * lg) + 1.0f);
    float val = fmaxf(g, 0.0f);

    if (kind == 2) { out[BB + b] = val; return; }

    red[tid] = ws[WS_CCW + s] * val;
    __syncthreads();
    if (tid < TBR) {
        float sum = 0.0f;
        for (int i = 0; i < NS; ++i) sum += red[tid * NS + i];
        int bo = b_base + tid;
        if (bo < BB) {
            if (kind == 0) {
                float xb = mode ? xarr[bo] : oml * xm[bo];
                out[bo] = sum * xb * 0.5f;
            } else {
                float x2b = mode ? x2arr[bo] : oml * xm[bo];
                out[2 * BB + bo] = sum * (xmax - x2b) * 0.5f * INV_ALPHA;
            }
        }
    }
}

extern "C" void kernel_launch(void* const* d_in, const int* in_sizes, int n_in,
                              void* d_out, int out_size, void* d_ws, size_t ws_size,
                              hipStream_t stream) {
    const float* x_  = (const float*)d_in[0];
    const float* h_  = (const float*)d_in[1];
    const float* lw  = (const float*)d_in[2];
    const float* sp  = (const float*)d_in[3];
    const float* f1W0 = (const float*)d_in[4];   const float* f1b0 = (const float*)d_in[5];
    const float* f1W1 = (const float*)d_in[6];   const float* f1b1 = (const float*)d_in[7];
    const float* f1W2 = (const float*)d_in[8];   const float* f1b2 = (const float*)d_in[9];
    const float* f1W3 = (const float*)d_in[10];  const float* f1b3 = (const float*)d_in[11];
    const float* f1Wf = (const float*)d_in[12];
    const float* f2W0 = (const float*)d_in[13];  const float* f2b0 = (const float*)d_in[14];
    const float* f2W1 = (const float*)d_in[15];  const float* f2b1 = (const float*)d_in[16];
    const float* f2W2 = (const float*)d_in[17];  const float* f2b2 = (const float*)d_in[18];
    const float* f2W3 = (const float*)d_in[19];  const float* f2b3 = (const float*)d_in[20];
    const float* f2Wf = (const float*)d_in[21];
    float* out = (float*)d_out;
    float* ws  = (float*)d_ws;

    k_setup<<<81, 256, 0, stream>>>(x_, lw, sp,
                                    f1W0, f1W1, f1W2, f1W3,
                                    f2W0, f2W1, f2W2, f2W3, ws);
    k_int<<<GRID_INT, 256, 0, stream>>>(0, ws, h_,
        f1b0, f1b1, f1b2, f1b3, f1Wf, f2b0, f2b1, f2b2, f2b3, f2Wf, out);
    k_pre<<<16, 256, 0, stream>>>(ws + WS_XM, out, ws + WS_LAM,
                                  ws + WS_X, ws + WS_X2, ws + WS_PM16);
    k_int<<<GRID_INT, 256, 0, stream>>>(1, ws, h_,
        f1b0, f1b1, f1b2, f1b3, f1Wf, f2b0, f2b1, f2b2, f2b3, f2Wf, out);
}

// Round 5
// 162.631 us; speedup vs baseline: 2.9176x; 1.0144x over previous
//
#include <hip/hip_runtime.h>
#include <math.h>

typedef _Float16 half8v __attribute__((ext_vector_type(8)));
typedef _Float16 half4v __attribute__((ext_vector_type(4)));
typedef float float4v __attribute__((ext_vector_type(4)));

// ---- problem constants ----
#define BB    4096
#define NS    51
#define TBR   5         // batch rows per integrate block (5*51=255 of 256 threads)
#define NBI   820       // ceil(4096/5)
#define NBF   16
#define GRID_INT (2*NBI + NBF)
#define INV_ALPHA (1.0f/0.9f)

// ---- workspace float offsets ----
#define WS_CCW 0
#define WS_CCS 64
#define WS_LAM 128
#define WS_KEY 132      // uint slot: order-preserving key of max(x2_step1)
#define WS_PM  144      // 256 block-maxes of xm
#define WS_XM  512
#define WS_X   (WS_XM + BB)
#define WS_X2  (WS_X + BB)
#define WS_H   16384    // halfs region starts at byte 65536
// half offsets within WS_H
#define H_NET  8192
#define H_W2   4096
#define H_W0   16384    // + net*2048 : [64 j][32 k] zero-padded
#define H_W3   20480    // + net*64

#if defined(__has_builtin)
#if __has_builtin(__builtin_amdgcn_rcpf)
#define FRCP(x) __builtin_amdgcn_rcpf(x)
#endif
#endif
#ifndef FRCP
#define FRCP(x) (1.0f / (x))
#endif

__device__ __forceinline__ unsigned fkey(float f) {
    int i = __float_as_int(f);
    return (i >= 0) ? ((unsigned)i + 0x80000000u) : ~(unsigned)i;
}
__device__ __forceinline__ float fkey_inv(unsigned k) {
    return (k & 0x80000000u) ? __int_as_float((int)(k - 0x80000000u))
                             : __int_as_float((int)~k);
}

// XOR-swizzled act addressing: 256 rows x 64 halfs (stride 64), 16B blocks
// permuted by row. Returns half index.
__device__ __forceinline__ int swz(int row, int cb) {
    return (row << 6) + (((cb ^ (row & 7)) & 7) << 3);
}

// ---- fused setup: xm + 256 partial maxes | weight repack | CC + lam + key ----
__global__ void k_setup(const float* __restrict__ x_, const float* __restrict__ lw,
                        const float* __restrict__ sp,
                        const float* __restrict__ f1W0, const float* __restrict__ f1W1,
                        const float* __restrict__ f1W2, const float* __restrict__ f1W3,
                        const float* __restrict__ f2W0, const float* __restrict__ f2W1,
                        const float* __restrict__ f2W2, const float* __restrict__ f2W3,
                        float* __restrict__ ws) {
    _Float16* wh = (_Float16*)(ws + WS_H);
    const int blk = blockIdx.x, tid = threadIdx.x;
    if (blk < 256) {
        int wave = tid >> 6, lane = tid & 63;
        float vmax = -1e30f;
        for (int r = 0; r < 4; ++r) {
            int row = blk * 16 + wave * 4 + r;
            float v = 0.0f;
            for (int i = lane; i < 100; i += 64) v = fmaf(x_[row * 100 + i], lw[i], v);
            #pragma unroll
            for (int off = 32; off > 0; off >>= 1) v += __shfl_xor(v, off, 64);
            if (lane == 0) ws[WS_XM + row] = v;
            vmax = fmaxf(vmax, v);
        }
        __shared__ float sm[4];
        if (lane == 0) sm[wave] = vmax;
        __syncthreads();
        if (tid == 0)
            ws[WS_PM + blk] = fmaxf(fmaxf(sm[0], sm[1]), fmaxf(sm[2], sm[3]));
    } else if (blk < 272) {
        int t = (blk - 256) * 256 + tid;       // 0..4095
        wh[t]                = (_Float16)f1W1[t];
        wh[H_W2 + t]         = (_Float16)f1W2[t];
        wh[H_NET + t]        = (_Float16)f2W1[t];
        wh[H_NET + H_W2 + t] = (_Float16)f2W2[t];
        if (t < 2048) {
            int j = t >> 5, k = t & 31;
            wh[H_W0 + t]        = (k < 5) ? (_Float16)f1W0[j * 5 + k] : (_Float16)0.0f;
            wh[H_W0 + 2048 + t] = (k < 5) ? (_Float16)f2W0[j * 5 + k] : (_Float16)0.0f;
        }
        if (t < 64) {
            wh[H_W3 + t]      = (_Float16)f1W3[t];
            wh[H_W3 + 64 + t] = (_Float16)f2W3[t];
        }
    } else {
        if (tid == 60) ws[WS_LAM] = 1.0f / (1.0f + expf(-sp[0]));
        if (tid == 61) ((unsigned*)ws)[WS_KEY] = 0u;   // key of -inf
        if (tid <= 50) {
            ws[WS_CCS + tid] = cospif((float)tid / 50.0f);
            float acc = 0.0f;
            for (int a = 0; a <= 50; ++a) {
                float w;
                if (a == 0) w = 1.0f;
                else if ((a & 1) == 0) w = 2.0f / (1.0f - (float)(a * a));
                else continue;
                float l;
                if (tid == 0) l = 0.5f;
                else {
                    int m = (a * tid) % 100;
                    l = cospif((float)m / 50.0f);
                    if (tid == 50) l *= 0.5f;
                }
                acc += l * 0.04f * w;
            }
            ws[WS_CCW + tid] = acc;
        }
    }
}

// hidden layer 64->64: OUT^T = W*ACT^T, per-wave 64-row tile, barrier-free.
__device__ __forceinline__ void mfma_hidden(
    const _Float16* __restrict__ Wg, const float* __restrict__ Bg,
    _Float16* act, int tid)
{
    const int lane = tid & 63, wbase = tid & 192;
    const int lo = lane & 15, quad = lane >> 4;
    half8v Af[4][2];
    #pragma unroll
    for (int m = 0; m < 4; ++m)
        #pragma unroll
        for (int kb = 0; kb < 2; ++kb)
            Af[m][kb] = *(const half8v*)(Wg + (16 * m + lo) * 64 + 32 * kb + quad * 8);
    float4v bb[4];
    #pragma unroll
    for (int m = 0; m < 4; ++m) bb[m] = *(const float4v*)(Bg + 16 * m + quad * 4);
    half8v Bf[4][2];
    #pragma unroll
    for (int n = 0; n < 4; ++n)
        #pragma unroll
        for (int kb = 0; kb < 2; ++kb)
            Bf[n][kb] = *(const half8v*)(act + swz(wbase + 16 * n + lo, 4 * kb + quad));
    float4v accv[4][4];
    #pragma unroll
    for (int m = 0; m < 4; ++m)
        #pragma unroll
        for (int n = 0; n < 4; ++n) {
            float4v c = bb[m];
            c = __builtin_amdgcn_mfma_f32_16x16x32_f16(Af[m][0], Bf[n][0], c, 0, 0, 0);
            c = __builtin_amdgcn_mfma_f32_16x16x32_f16(Af[m][1], Bf[n][1], c, 0, 0, 0);
            accv[m][n] = c;
        }
    #pragma unroll
    for (int m = 0; m < 4; ++m)
        #pragma unroll
        for (int n = 0; n < 4; ++n) {
            float4v c = accv[m][n];
            half4v o;
            o[0] = (_Float16)fmaxf(c[0], 0.0f); o[1] = (_Float16)fmaxf(c[1], 0.0f);
            o[2] = (_Float16)fmaxf(c[2], 0.0f); o[3] = (_Float16)fmaxf(c[3], 0.0f);
            *(half4v*)(act + swz(wbase + 16 * n + lo, 2 * m + (quad >> 1)) + 4 * (quad & 1)) = o;
        }
}

// first layer 5(pad 32)->64
__device__ __forceinline__ void mfma_first(
    const _Float16* __restrict__ Wg, const float* __restrict__ Bg,
    _Float16* act, int tid)
{
    const int lane = tid & 63, wbase = tid & 192;
    const int lo = lane & 15, quad = lane >> 4;
    half8v Af[4];
    #pragma unroll
    for (int m = 0; m < 4; ++m)
        Af[m] = *(const half8v*)(Wg + (16 * m + lo) * 32 + quad * 8);
    float4v bb[4];
    #pragma unroll
    for (int m = 0; m < 4; ++m) bb[m] = *(const float4v*)(Bg + 16 * m + quad * 4);
    half8v Bf[4];
    #pragma unroll
    for (int n = 0; n < 4; ++n)
        Bf[n] = *(const half8v*)(act + swz(wbase + 16 * n + lo, quad));
    float4v accv[4][4];
    #pragma unroll
    for (int m = 0; m < 4; ++m)
        #pragma unroll
        for (int n = 0; n < 4; ++n)
            accv[m][n] = __builtin_amdgcn_mfma_f32_16x16x32_f16(Af[m], Bf[n], bb[m], 0, 0, 0);
    #pragma unroll
    for (int m = 0; m < 4; ++m)
        #pragma unroll
        for (int n = 0; n < 4; ++n) {
            float4v c = accv[m][n];
            half4v o;
            o[0] = (_Float16)fmaxf(c[0], 0.0f); o[1] = (_Float16)fmaxf(c[1], 0.0f);
            o[2] = (_Float16)fmaxf(c[2], 0.0f); o[3] = (_Float16)fmaxf(c[3], 0.0f);
            *(half4v*)(act + swz(wbase + 16 * n + lo, 2 * m + (quad >> 1)) + 4 * (quad & 1)) = o;
        }
}

// Blocks [0,NBI): I1 (f1, 0->x). [NBI,2NBI): I2 (f2, x2->xmax). [2NBI,+NBF): out_first.
// mode 0: step0 (x=x2=(1-lam)*xm inline; xmax from PM; tails write x/x2/key).
// mode 1: step1 (read x/x2/key).
__global__ __launch_bounds__(256) void k_int(
    int mode, float* __restrict__ ws, const float* __restrict__ h_,
    const float* __restrict__ f1b0, const float* __restrict__ f1b1,
    const float* __restrict__ f1b2, const float* __restrict__ f1b3,
    const float* __restrict__ f1Wf,
    const float* __restrict__ f2b0, const float* __restrict__ f2b1,
    const float* __restrict__ f2b2, const float* __restrict__ f2b3,
    const float* __restrict__ f2Wf,
    float* __restrict__ out)
{
    __shared__ _Float16 act[256 * 64];     // 32 KB; red[] aliased after barrier
    float* red = (float*)act;

    const int blk = blockIdx.x, tid = threadIdx.x;
    const float* xm = ws + WS_XM;
    const float* xarr = ws + WS_X;
    const float* x2arr = ws + WS_X2;
    const _Float16* wh = (const _Float16*)(ws + WS_H);
    const float lam = ws[WS_LAM];
    const float oml = 1.0f - lam;

    int kind, b_base = 0, b, s = 0;
    if (blk < NBI)          { kind = 0; b_base = blk * TBR; }
    else if (blk < 2 * NBI) { kind = 1; b_base = (blk - NBI) * TBR; }
    else                    { kind = 2; }

    float xmax = 0.0f, xin;
    if (kind == 2) {
        b = (blk - 2 * NBI) * 256 + tid;
        xin = mode ? x2arr[b] : oml * xm[b];
    } else {
        if (kind == 1) {
            if (mode) {
                xmax = fkey_inv(((const unsigned*)ws)[WS_KEY]) + 10.0f;
            } else {
                int lane = tid & 63;
                const float* pm = ws + WS_PM;
                float v = fmaxf(fmaxf(pm[lane], pm[lane + 64]),
                                fmaxf(pm[lane + 128], pm[lane + 192]));
                #pragma unroll
                for (int off = 32; off > 0; off >>= 1) v = fmaxf(v, __shfl_xor(v, off, 64));
                xmax = oml * v + 10.0f;
            }
        }
        int lb = tid / 51;
        s = tid - lb * 51;
        b = b_base + (lb < TBR - 1 ? lb : TBR - 1);
        if (b > BB - 1) b = BB - 1;
        float t = (ws[WS_CCS + s] + 1.0f) * 0.5f;
        if (kind == 0) {
            float xb = mode ? xarr[b] : oml * xm[b];
            xin = xb * t;
        } else {
            float x0v = mode ? x2arr[b] : oml * xm[b];
            xin = x0v + (xmax - x0v) * t;
        }
    }
    const float4 h4 = ((const float4*)h_)[b];

    const bool u2 = (kind == 1);
    const _Float16* W0h = wh + H_W0 + (u2 ? 2048 : 0);
    const _Float16* W1h = wh + (u2 ? H_NET : 0);
    const _Float16* W2h = W1h + H_W2;
    const _Float16* W3h = wh + H_W3 + (u2 ? 64 : 0);
    const float* B0 = u2 ? f2b0 : f1b0;
    const float* B1 = u2 ? f2b1 : f1b1;
    const float* B2 = u2 ? f2b2 : f1b2;
    const float* B3 = u2 ? f2b3 : f1b3;
    const float* WF = u2 ? f2Wf : f1Wf;
    const float p0 = u2 ? 1.5f : 1.1f;
    const float p1 = u2 ? 2.0f : 1.1f;
    const float p2 = u2 ? 2.5f : 1.5f;
    const float p3 = u2 ? 3.0f : 2.0f;
    const float p4 = u2 ? 3.5f : 2.5f;

    // stage padded K=32 input row (own row only; per-wave DS is in-order)
    {
        half8v sv;
        sv[0] = (_Float16)xin; sv[1] = (_Float16)h4.x; sv[2] = (_Float16)h4.y;
        sv[3] = (_Float16)h4.z; sv[4] = (_Float16)h4.w;
        sv[5] = (_Float16)0.0f; sv[6] = (_Float16)0.0f; sv[7] = (_Float16)0.0f;
        half8v zv;
        #pragma unroll
        for (int e = 0; e < 8; ++e) zv[e] = (_Float16)0.0f;
        *(half8v*)(act + swz(tid, 0)) = sv;
        *(half8v*)(act + swz(tid, 1)) = zv;
        *(half8v*)(act + swz(tid, 2)) = zv;
        *(half8v*)(act + swz(tid, 3)) = zv;
    }

    mfma_first (W0h, B0, act, tid);
    mfma_hidden(W1h, B1, act, tid);
    mfma_hidden(W2h, B2, act, tid);

    // final 64->1 dot + epilogue
    float y = B3[0];
    #pragma unroll
    for (int g = 0; g < 8; ++g) {
        half8v hv = *(const half8v*)(act + swz(tid, g));
        half8v wv = *(const half8v*)(W3h + 8 * g);
        #pragma unroll
        for (int e = 0; e < 8; ++e) y = fmaf((float)wv[e], (float)hv[e], y);
    }
    if (y <= 0.0f) y = __expf(y) - 1.0f;   // elu
    float z = y + 1.0f;
    float lg = __logf(z);
    float g = WF[0] * FRCP(__expf(p0 * lg) + 1.0f)
            + WF[1] * FRCP(__expf(p1 * lg) + 1.0f)
            + WF[2] * FRCP(__expf(p2 * lg) + 1.0f)
            + WF[3] * FRCP(__expf(p3 * lg) + 1.0f)
            + WF[4] * FRCP(__expf(p4 * lg) + 1.0f);
    float val = fmaxf(g, 0.0f);

    if (kind == 2) { out[BB + b] = val; return; }   // whole block returns together

    __syncthreads();                 // all waves done with act before aliasing red
    red[tid] = ws[WS_CCW + s] * val;
    __syncthreads();

    if (kind == 0) {
        if (tid < TBR) {
            float sum = 0.0f;
            for (int i = 0; i < NS; ++i) sum += red[tid * NS + i];
            int bo = b_base + tid;
            if (bo < BB) {
                float xb = mode ? xarr[bo] : oml * xm[bo];
                float I1 = sum * xb * 0.5f;
                out[bo] = I1;
                if (!mode) ws[WS_X + bo] = oml * xm[bo] + lam * I1;  // x for step1
            }
        }
    } else {
        float x2n = -3e38f;
        if (tid < TBR) {
            float sum = 0.0f;
            for (int i = 0; i < NS; ++i) sum += red[tid * NS + i];
            int bo = b_base + tid;
            if (bo < BB) {
                float x2b = mode ? x2arr[bo] : oml * xm[bo];
                float I2 = sum * (xmax - x2b) * 0.5f * INV_ALPHA;
                out[2 * BB + bo] = I2;
                if (!mode) {
                    x2n = oml * xm[bo] + lam * I2;                   // x2 for step1
                    ws[WS_X2 + bo] = x2n;
                }
            }
        }
        if (!mode && tid < 64) {
            #pragma unroll
            for (int off = 32; off > 0; off >>= 1)
                x2n = fmaxf(x2n, __shfl_xor(x2n, off, 64));
            if (tid == 0) atomicMax((unsigned*)ws + WS_KEY, fkey(x2n));
        }
    }
}

extern "C" void kernel_launch(void* const* d_in, const int* in_sizes, int n_in,
                              void* d_out, int out_size, void* d_ws, size_t ws_size,
                              hipStream_t stream) {
    const float* x_  = (const float*)d_in[0];
    const float* h_  = (const float*)d_in[1];
    const float* lw  = (const float*)d_in[2];
    const float* sp  = (const float*)d_in[3];
    const float* f1W0 = (const float*)d_in[4];   const float* f1b0 = (const float*)d_in[5];
    const float* f1W1 = (const float*)d_in[6];   const float* f1b1 = (const float*)d_in[7];
    const float* f1W2 = (const float*)d_in[8];   const float* f1b2 = (const float*)d_in[9];
    const float* f1W3 = (const float*)d_in[10];  const float* f1b3 = (const float*)d_in[11];
    const float* f1Wf = (const float*)d_in[12];
    const float* f2W0 = (const float*)d_in[13];  const float* f2b0 = (const float*)d_in[14];
    const float* f2W1 = (const float*)d_in[15];  const float* f2b1 = (const float*)d_in[16];
    const float* f2W2 = (const float*)d_in[17];  const float* f2b2 = (const float*)d_in[18];
    const float* f2W3 = (const float*)d_in[19];  const float* f2b3 = (const float*)d_in[20];
    const float* f2Wf = (const float*)d_in[21];
    float* out = (float*)d_out;
    float* ws  = (float*)d_ws;

    k_setup<<<273, 256, 0, stream>>>(x_, lw, sp,
                                     f1W0, f1W1, f1W2, f1W3,
                                     f2W0, f2W1, f2W2, f2W3, ws);
    k_int<<<GRID_INT, 256, 0, stream>>>(0, ws, h_,
        f1b0, f1b1, f1b2, f1b3, f1Wf, f2b0, f2b1, f2b2, f2b3, f2Wf, out);
    k_int<<<GRID_INT, 256, 0, stream>>>(1, ws, h_,
        f1b0, f1b1, f1b2, f1b3, f1Wf, f2b0, f2b1, f2b2, f2b3, f2Wf, out);
}